// Round 10
// baseline (988.272 us; speedup 1.0000x reference)
//
#include <hip/hip_runtime.h>

#define NN 100000
#define NE 1600000
#define HID 128
#define OUT_DIM 10
#define N_CONV 4
#define N_GRAPHS 128

#define NBUCK 196                      // ceil(NN / 512) coarse dst-buckets
#define CCHUNK 4096                    // edges per scatter block
#define NCB ((NE + CCHUNK - 1) / CCHUNK)   // 391 blocks

typedef float nfloat4 __attribute__((ext_vector_type(4)));  // native vec for NT builtins

// ---------------- zero: pool accumulator + coarse histogram ----------------

__global__ __launch_bounds__(256) void k_zero(float* __restrict__ g,
                                              int* __restrict__ coarse_cnt) {
  int i = blockIdx.x * 256 + threadIdx.x;
  if (i < N_GRAPHS * HID) g[i] = 0.0f;
  if (i < NBUCK + 1) coarse_cnt[i] = 0;
}

// ---------------- coarse histogram over dst>>9 ----------------

__global__ __launch_bounds__(256) void k_hist(const int* __restrict__ ecol,
                                              int* __restrict__ coarse_cnt) {
  __shared__ int cnt[NBUCK];
  for (int i = threadIdx.x; i < NBUCK; i += 256) cnt[i] = 0;
  __syncthreads();
  int base = blockIdx.x * CCHUNK;
#pragma unroll
  for (int i = 0; i < 16; ++i) {
    int e = base + i * 256 + threadIdx.x;
    if (e < NE) atomicAdd(&cnt[ecol[e] >> 9], 1);
  }
  __syncthreads();
  for (int i = threadIdx.x; i < NBUCK; i += 256)
    if (cnt[i]) atomicAdd(&coarse_cnt[i], cnt[i]);
}

// ---------------- scan coarse buckets -> bases, init cursors ----------------

__global__ __launch_bounds__(256) void k_scanb(const int* __restrict__ coarse_cnt,
                                               int* __restrict__ bucket_base,
                                               int* __restrict__ bcur,
                                               int* __restrict__ row_ptr) {
  __shared__ int s[256];
  int t = threadIdx.x;
  int v = (t < NBUCK) ? coarse_cnt[t] : 0;
  s[t] = v;
  __syncthreads();
  for (int off = 1; off < 256; off <<= 1) {
    int u = (t >= off) ? s[t - off] : 0;
    __syncthreads();
    s[t] += u;
    __syncthreads();
  }
  if (t < NBUCK) {
    int excl = s[t] - v;
    bucket_base[t] = excl;
    bcur[t] = excl;
  }
  if (t == 0) { bucket_base[NBUCK] = NE; row_ptr[NN] = NE; }
}

// ---- scatter edges into coarse-bucket regions with LDS reorder (locality) ----
// edge_buf entry: src | (dst&511)<<17   (src<2^17, dlocal<2^9 -> 26 bits)

__global__ __launch_bounds__(256) void k_scatter(const int* __restrict__ erow,
                                                 const int* __restrict__ ecol,
                                                 int* __restrict__ bcur,
                                                 int* __restrict__ edge_buf) {
  __shared__ int rs[CCHUNK];
  __shared__ unsigned char rb[CCHUNK];
  __shared__ int cnt[NBUCK + 1];
  __shared__ int lbase[NBUCK + 1];
  __shared__ int lcur[NBUCK + 1];
  __shared__ int grun[NBUCK];
  __shared__ int sscan[256];
  __shared__ int sTotal;

  const int t = threadIdx.x;
  const int base = blockIdx.x * CCHUNK;

  for (int i = t; i < NBUCK + 1; i += 256) cnt[i] = 0;
  __syncthreads();

  int myb[16];
#pragma unroll
  for (int i = 0; i < 16; ++i) {
    int e = base + i * 256 + t;
    int b = NBUCK;
    if (e < NE) b = ecol[e] >> 9;
    myb[i] = b;
    if (b < NBUCK) atomicAdd(&cnt[b], 1);
  }
  __syncthreads();

  // exclusive scan of cnt[0..NBUCK)
  int cv = (t < NBUCK) ? cnt[t] : 0;
  sscan[t] = cv;
  __syncthreads();
  for (int off = 1; off < 256; off <<= 1) {
    int u = (t >= off) ? sscan[t - off] : 0;
    __syncthreads();
    sscan[t] += u;
    __syncthreads();
  }
  if (t < NBUCK) {
    int excl = sscan[t] - cv;
    lbase[t] = excl;
    lcur[t] = excl;
    if (cv > 0) grun[t] = atomicAdd(&bcur[t], cv);
  }
  if (t == 255) sTotal = sscan[255];
  __syncthreads();

  // reorder into LDS by bucket
#pragma unroll
  for (int i = 0; i < 16; ++i) {
    int b = myb[i];
    if (b < NBUCK) {
      int e = base + i * 256 + t;
      int packed = erow[e] | ((ecol[e] & 511) << 17);
      int pos = atomicAdd(&lcur[b], 1);
      rs[pos] = packed;
      rb[pos] = (unsigned char)b;
    }
  }
  __syncthreads();

  // copy out contiguous runs
  int total = sTotal;
  for (int pos = t; pos < total; pos += 256) {
    int b = rb[pos];
    edge_buf[grun[b] + (pos - lbase[b])] = rs[pos];
  }
}

// ---- per-bucket CSR build: counts, row_ptr, dinv, src scatter (L2-local) ----

__global__ __launch_bounds__(512) void k_build(const int* __restrict__ bucket_base,
                                               const int* __restrict__ edge_buf,
                                               int* __restrict__ row_ptr,
                                               float* __restrict__ dinv,
                                               int* __restrict__ csr_src) {
  __shared__ int cnt[512];
  __shared__ int s[512];
  __shared__ int cur[512];
  const int b = blockIdx.x;
  const int t = threadIdx.x;
  const int r0 = bucket_base[b];
  const int r1 = bucket_base[b + 1];

  cnt[t] = 0;
  __syncthreads();
  for (int e = r0 + t; e < r1; e += 512) {
    int dl = ((unsigned)edge_buf[e]) >> 17;
    atomicAdd(&cnt[dl], 1);
  }
  __syncthreads();
  s[t] = cnt[t];
  __syncthreads();
  for (int off = 1; off < 512; off <<= 1) {
    int u = (t >= off) ? s[t - off] : 0;
    __syncthreads();
    s[t] += u;
    __syncthreads();
  }
  int node = b * 512 + t;
  int excl = s[t] - cnt[t];
  if (node < NN) {
    row_ptr[node] = r0 + excl;
    dinv[node] = rsqrtf((float)(cnt[t] + 1));  // +1 self-loop
  }
  cur[t] = r0 + excl;
  __syncthreads();
  for (int e = r0 + t; e < r1; e += 512) {
    int v = edge_buf[e];
    int dl = ((unsigned)v) >> 17;
    int pos = atomicAdd(&cur[dl], 1);
    csr_src[pos] = v & 0x1FFFF;
  }
}

// ---------------- fp32 GEMM v3: out[N,128] = A[N,128] @ W[128,128] ----------------
// 256-row tile, 256 threads, thread-tile 8 rows x 16 cols, K-tile 32.
// rg = tid>>3 (0..31): rows rg+32*i; cg = tid&7: col float4s (cg+8q), q=0..3
// -> B-reads hit 8 distinct bank-quads (no alias); 24 ds_read_b128 per 512 FMA.

__global__ __launch_bounds__(256, 2) void gemm256(const float* __restrict__ A,
                                                  const float* __restrict__ W,
                                                  float* __restrict__ out,
                                                  const float* __restrict__ bias,
                                                  int relu,
                                                  const float* __restrict__ rowscale,
                                                  int N) {
  __shared__ float sA[256 * 36];   // row r at sA[r*36], 32 floats used
  __shared__ float sW[32 * 132];   // k-row at sW[k*132], 128 floats used
  const int tid = threadIdx.x;
  const int rg = tid >> 3;   // 0..31
  const int cg = tid & 7;    // 0..7
  const int rowBase = blockIdx.x * 256;

  float4 acc[8][4];
#pragma unroll
  for (int i = 0; i < 8; ++i)
#pragma unroll
    for (int q = 0; q < 4; ++q) acc[i][q] = make_float4(0.f, 0.f, 0.f, 0.f);

  for (int kc = 0; kc < 128; kc += 32) {
    // stage A: per rep, 32 rows x 8 f4-cols; lane = (row%32, f4col) -> coalesced
#pragma unroll
    for (int rep = 0; rep < 8; ++rep) {
      int rl = rep * 32 + (tid >> 3);
      int row = rowBase + rl;
      float4 v = make_float4(0.f, 0.f, 0.f, 0.f);
      if (row < N) v = *(const float4*)&A[(size_t)row * 128 + kc + (tid & 7) * 4];
      *(float4*)&sA[rl * 36 + (tid & 7) * 4] = v;
    }
    // stage W: k = tid>>3 (0..31), 4 f4 at (tid&7)+8j -> coalesced
    {
      int k = tid >> 3;
      const float* src = &W[(size_t)(kc + k) * 128];
#pragma unroll
      for (int j = 0; j < 4; ++j) {
        int f4 = (tid & 7) + 8 * j;
        *(float4*)&sW[k * 132 + f4 * 4] = *(const float4*)&src[f4 * 4];
      }
    }
    __syncthreads();

#pragma unroll
    for (int kk = 0; kk < 32; kk += 4) {
      float4 a[8];
#pragma unroll
      for (int i = 0; i < 8; ++i)
        a[i] = *(float4*)&sA[(rg + 32 * i) * 36 + kk];
#pragma unroll
      for (int j = 0; j < 4; ++j) {
        float4 b[4];
#pragma unroll
        for (int q = 0; q < 4; ++q)
          b[q] = *(float4*)&sW[(kk + j) * 132 + (cg + 8 * q) * 4];
#pragma unroll
        for (int i = 0; i < 8; ++i) {
          float av = (j == 0) ? a[i].x : (j == 1) ? a[i].y : (j == 2) ? a[i].z : a[i].w;
#pragma unroll
          for (int q = 0; q < 4; ++q) {
            acc[i][q].x += av * b[q].x;
            acc[i][q].y += av * b[q].y;
            acc[i][q].z += av * b[q].z;
            acc[i][q].w += av * b[q].w;
          }
        }
      }
    }
    __syncthreads();
  }

  float4 bv[4];
#pragma unroll
  for (int q = 0; q < 4; ++q)
    bv[q] = bias ? *(const float4*)&bias[(cg + 8 * q) * 4]
                 : make_float4(0.f, 0.f, 0.f, 0.f);
#pragma unroll
  for (int i = 0; i < 8; ++i) {
    int row = rowBase + rg + 32 * i;
    if (row < N) {
      float sc = rowscale ? rowscale[row] : 1.0f;
#pragma unroll
      for (int q = 0; q < 4; ++q) {
        float4 v;
        v.x = (acc[i][q].x + bv[q].x) * sc;
        v.y = (acc[i][q].y + bv[q].y) * sc;
        v.z = (acc[i][q].z + bv[q].z) * sc;
        v.w = (acc[i][q].w + bv[q].w) * sc;
        if (relu) {
          v.x = fmaxf(v.x, 0.f); v.y = fmaxf(v.y, 0.f);
          v.z = fmaxf(v.z, 0.f); v.w = fmaxf(v.w, 0.f);
        }
        *(float4*)&out[(size_t)row * 128 + (cg + 8 * q) * 4] = v;
      }
    }
  }
}

// ---- fused aggregation: h[i] = relu(dinv_i*(sum_in m'[src] + m'[i]) + bias) ----
// NT load for streamed csr_src, NT store for h (protect m rows in L2).

__global__ __launch_bounds__(256) void gather_fused(const float* __restrict__ m,
                                                    const int* __restrict__ row_ptr,
                                                    const int* __restrict__ csr_src,
                                                    const float* __restrict__ dinv,
                                                    const float* __restrict__ bias,
                                                    float* __restrict__ h) {
  int t = blockIdx.x * 256 + threadIdx.x;
  int node = t >> 5;
  if (node >= NN) return;
  int lane = t & 31;

  float4 a0 = *(const float4*)&m[(size_t)node * 128 + lane * 4];  // self (pre-scaled)
  float4 a1 = make_float4(0.f, 0.f, 0.f, 0.f);
  float4 a2 = make_float4(0.f, 0.f, 0.f, 0.f);
  float4 a3 = make_float4(0.f, 0.f, 0.f, 0.f);

  int beg = row_ptr[node];
  int end = row_ptr[node + 1];

  int k = beg;
  for (; k + 3 < end; k += 4) {
    int s0 = __builtin_nontemporal_load(&csr_src[k]);
    int s1 = __builtin_nontemporal_load(&csr_src[k + 1]);
    int s2 = __builtin_nontemporal_load(&csr_src[k + 2]);
    int s3 = __builtin_nontemporal_load(&csr_src[k + 3]);
    float4 v0 = *(const float4*)&m[(size_t)s0 * 128 + lane * 4];
    float4 v1 = *(const float4*)&m[(size_t)s1 * 128 + lane * 4];
    float4 v2 = *(const float4*)&m[(size_t)s2 * 128 + lane * 4];
    float4 v3 = *(const float4*)&m[(size_t)s3 * 128 + lane * 4];
    a0.x += v0.x; a0.y += v0.y; a0.z += v0.z; a0.w += v0.w;
    a1.x += v1.x; a1.y += v1.y; a1.z += v1.z; a1.w += v1.w;
    a2.x += v2.x; a2.y += v2.y; a2.z += v2.z; a2.w += v2.w;
    a3.x += v3.x; a3.y += v3.y; a3.z += v3.z; a3.w += v3.w;
  }
  for (; k < end; ++k) {
    int s = __builtin_nontemporal_load(&csr_src[k]);
    float4 v = *(const float4*)&m[(size_t)s * 128 + lane * 4];
    a0.x += v.x; a0.y += v.y; a0.z += v.z; a0.w += v.w;
  }
  a0.x += a1.x + a2.x + a3.x;
  a0.y += a1.y + a2.y + a3.y;
  a0.z += a1.z + a2.z + a3.z;
  a0.w += a1.w + a2.w + a3.w;

  float dn = dinv[node];
  float4 b = *(const float4*)&bias[lane * 4];
  nfloat4 o;
  o.x = fmaxf(a0.x * dn + b.x, 0.f);
  o.y = fmaxf(a0.y * dn + b.y, 0.f);
  o.z = fmaxf(a0.z * dn + b.z, 0.f);
  o.w = fmaxf(a0.w * dn + b.w, 0.f);
  __builtin_nontemporal_store(o, (nfloat4*)&h[(size_t)node * 128 + lane * 4]);
}

// ---------------- pooling: g[batch[i]] += h[i], batch sorted ----------------

__global__ __launch_bounds__(128) void pool_kernel(const float* __restrict__ h,
                                                   const int* __restrict__ batch,
                                                   float* __restrict__ g) {
  int d = threadIdx.x;
  int chunk = (NN + gridDim.x - 1) / gridDim.x;
  int r0 = blockIdx.x * chunk;
  int r1 = min(NN, r0 + chunk);
  if (r0 >= r1) return;
  float acc = 0.f;
  int cur = batch[r0];
  for (int r = r0; r < r1; ++r) {
    int b = batch[r];
    if (b != cur) {
      atomicAdd(&g[(size_t)cur * HID + d], acc);
      acc = 0.f;
      cur = b;
    }
    acc += h[(size_t)r * HID + d];
  }
  atomicAdd(&g[(size_t)cur * HID + d], acc);
}

// ---------------- decode: out[128,10] = g @ dec_W + dec_b ----------------

__global__ __launch_bounds__(256) void decode_kernel(const float* __restrict__ g,
                                                     const float* __restrict__ W,
                                                     const float* __restrict__ b,
                                                     float* __restrict__ out) {
  int idx = blockIdx.x * 256 + threadIdx.x;
  if (idx >= N_GRAPHS * OUT_DIM) return;
  int gi = idx / OUT_DIM;
  int o = idx % OUT_DIM;
  float acc = b[o];
#pragma unroll 8
  for (int k = 0; k < HID; ++k) acc += g[(size_t)gi * HID + k] * W[k * OUT_DIM + o];
  out[idx] = acc;
}

// ---------------- launch ----------------

extern "C" void kernel_launch(void* const* d_in, const int* in_sizes, int n_in,
                              void* d_out, int out_size, void* d_ws, size_t ws_size,
                              hipStream_t stream) {
  const float* x      = (const float*)d_in[0];
  const float* enc_W  = (const float*)d_in[1];
  const float* enc_b  = (const float*)d_in[2];
  const float* conv_W = (const float*)d_in[3];
  const float* conv_b = (const float*)d_in[4];
  const float* dec_W  = (const float*)d_in[5];
  const float* dec_b  = (const float*)d_in[6];
  const int*   erow   = (const int*)d_in[7];
  const int*   ecol   = ((const int*)d_in[7]) + NE;
  const int*   batch  = (const int*)d_in[8];
  float* out = (float*)d_out;

  float* h          = (float*)d_ws;               // 12.8M f
  float* m          = h + (size_t)12800000;       // 12.8M f
  float* dinv       = m + (size_t)12800000;       // 100352 f
  float* g          = dinv + 100352;              // 16384 f
  int*   row_ptr    = (int*)(g + 16384);          // 100352 i (NN+1 used)
  int*   csr_src    = row_ptr + 100352;           // 1.6M i
  int*   edge_buf   = csr_src + 1600000;          // 1.6M i
  int*   coarse_cnt = edge_buf + 1600000;         // 256 i
  int*   bucket_base= coarse_cnt + 256;           // 256 i
  int*   bcur       = bucket_base + 256;          // 256 i

  const int gemmBlocks = (NN + 255) / 256;
  const int nodeBlocks = (NN * 32 + 255) / 256;

  // ---- CSR build (two-level counting sort) ----
  k_zero<<<64, 256, 0, stream>>>(g, coarse_cnt);
  k_hist<<<NCB, 256, 0, stream>>>(ecol, coarse_cnt);
  k_scanb<<<1, 256, 0, stream>>>(coarse_cnt, bucket_base, bcur, row_ptr);
  k_scatter<<<NCB, 256, 0, stream>>>(erow, ecol, bcur, edge_buf);
  k_build<<<NBUCK, 512, 0, stream>>>(bucket_base, edge_buf, row_ptr, dinv, csr_src);

  // ---- encode ----
  gemm256<<<gemmBlocks, 256, 0, stream>>>(x, enc_W, h, enc_b, 1, nullptr, NN);

  // ---- conv layers ----
  for (int l = 0; l < N_CONV; ++l) {
    const float* Wl = conv_W + (size_t)l * 128 * 128;
    const float* bl = conv_b + (size_t)l * 128;
    gemm256<<<gemmBlocks, 256, 0, stream>>>(h, Wl, m, nullptr, 0, dinv, NN);
    gather_fused<<<nodeBlocks, 256, 0, stream>>>(m, row_ptr, csr_src, dinv, bl, h);
  }

  // ---- pooling + decode ----
  pool_kernel<<<2048, 128, 0, stream>>>(h, batch, g);
  decode_kernel<<<(N_GRAPHS * OUT_DIM + 255) / 256, 256, 0, stream>>>(g, dec_W, dec_b, out);
}

// Round 11
// 749.227 us; speedup vs baseline: 1.3191x; 1.3191x over previous
//
#include <hip/hip_runtime.h>
#include <hip/hip_fp16.h>

#define NN 100000
#define NE 1600000
#define HID 128
#define OUT_DIM 10
#define N_CONV 4
#define N_GRAPHS 128

#define NBUCK 196                      // ceil(NN / 512) coarse dst-buckets
#define CCHUNK 4096                    // edges per scatter block
#define NCB ((NE + CCHUNK - 1) / CCHUNK)   // 391 blocks

// ---------------- zero: pool accumulator + coarse histogram ----------------

__global__ __launch_bounds__(256) void k_zero(float* __restrict__ g,
                                              int* __restrict__ coarse_cnt) {
  int i = blockIdx.x * 256 + threadIdx.x;
  if (i < N_GRAPHS * HID) g[i] = 0.0f;
  if (i < NBUCK + 1) coarse_cnt[i] = 0;
}

// ---------------- coarse histogram over dst>>9 ----------------

__global__ __launch_bounds__(256) void k_hist(const int* __restrict__ ecol,
                                              int* __restrict__ coarse_cnt) {
  __shared__ int cnt[NBUCK];
  for (int i = threadIdx.x; i < NBUCK; i += 256) cnt[i] = 0;
  __syncthreads();
  int base = blockIdx.x * CCHUNK;
#pragma unroll
  for (int i = 0; i < 16; ++i) {
    int e = base + i * 256 + threadIdx.x;
    if (e < NE) atomicAdd(&cnt[ecol[e] >> 9], 1);
  }
  __syncthreads();
  for (int i = threadIdx.x; i < NBUCK; i += 256)
    if (cnt[i]) atomicAdd(&coarse_cnt[i], cnt[i]);
}

// ---------------- scan coarse buckets -> bases, init cursors ----------------

__global__ __launch_bounds__(256) void k_scanb(const int* __restrict__ coarse_cnt,
                                               int* __restrict__ bucket_base,
                                               int* __restrict__ bcur,
                                               int* __restrict__ row_ptr) {
  __shared__ int s[256];
  int t = threadIdx.x;
  int v = (t < NBUCK) ? coarse_cnt[t] : 0;
  s[t] = v;
  __syncthreads();
  for (int off = 1; off < 256; off <<= 1) {
    int u = (t >= off) ? s[t - off] : 0;
    __syncthreads();
    s[t] += u;
    __syncthreads();
  }
  if (t < NBUCK) {
    int excl = s[t] - v;
    bucket_base[t] = excl;
    bcur[t] = excl;
  }
  if (t == 0) { bucket_base[NBUCK] = NE; row_ptr[NN] = NE; }
}

// ---- scatter edges into coarse-bucket regions with LDS reorder (locality) ----
// edge_buf entry: src | (dst&511)<<17   (src<2^17, dlocal<2^9 -> 26 bits)

__global__ __launch_bounds__(256) void k_scatter(const int* __restrict__ erow,
                                                 const int* __restrict__ ecol,
                                                 int* __restrict__ bcur,
                                                 int* __restrict__ edge_buf) {
  __shared__ int rs[CCHUNK];
  __shared__ unsigned char rb[CCHUNK];
  __shared__ int cnt[NBUCK + 1];
  __shared__ int lbase[NBUCK + 1];
  __shared__ int lcur[NBUCK + 1];
  __shared__ int grun[NBUCK];
  __shared__ int sscan[256];
  __shared__ int sTotal;

  const int t = threadIdx.x;
  const int base = blockIdx.x * CCHUNK;

  for (int i = t; i < NBUCK + 1; i += 256) cnt[i] = 0;
  __syncthreads();

  int myb[16];
#pragma unroll
  for (int i = 0; i < 16; ++i) {
    int e = base + i * 256 + t;
    int b = NBUCK;
    if (e < NE) b = ecol[e] >> 9;
    myb[i] = b;
    if (b < NBUCK) atomicAdd(&cnt[b], 1);
  }
  __syncthreads();

  // exclusive scan of cnt[0..NBUCK)
  int cv = (t < NBUCK) ? cnt[t] : 0;
  sscan[t] = cv;
  __syncthreads();
  for (int off = 1; off < 256; off <<= 1) {
    int u = (t >= off) ? sscan[t - off] : 0;
    __syncthreads();
    sscan[t] += u;
    __syncthreads();
  }
  if (t < NBUCK) {
    int excl = sscan[t] - cv;
    lbase[t] = excl;
    lcur[t] = excl;
    if (cv > 0) grun[t] = atomicAdd(&bcur[t], cv);
  }
  if (t == 255) sTotal = sscan[255];
  __syncthreads();

  // reorder into LDS by bucket
#pragma unroll
  for (int i = 0; i < 16; ++i) {
    int b = myb[i];
    if (b < NBUCK) {
      int e = base + i * 256 + t;
      int packed = erow[e] | ((ecol[e] & 511) << 17);
      int pos = atomicAdd(&lcur[b], 1);
      rs[pos] = packed;
      rb[pos] = (unsigned char)b;
    }
  }
  __syncthreads();

  // copy out contiguous runs
  int total = sTotal;
  for (int pos = t; pos < total; pos += 256) {
    int b = rb[pos];
    edge_buf[grun[b] + (pos - lbase[b])] = rs[pos];
  }
}

// ---- per-bucket CSR build: counts, row_ptr, dinv, src scatter (L2-local) ----

__global__ __launch_bounds__(512) void k_build(const int* __restrict__ bucket_base,
                                               const int* __restrict__ edge_buf,
                                               int* __restrict__ row_ptr,
                                               float* __restrict__ dinv,
                                               int* __restrict__ csr_src) {
  __shared__ int cnt[512];
  __shared__ int s[512];
  __shared__ int cur[512];
  const int b = blockIdx.x;
  const int t = threadIdx.x;
  const int r0 = bucket_base[b];
  const int r1 = bucket_base[b + 1];

  cnt[t] = 0;
  __syncthreads();
  for (int e = r0 + t; e < r1; e += 512) {
    int dl = ((unsigned)edge_buf[e]) >> 17;
    atomicAdd(&cnt[dl], 1);
  }
  __syncthreads();
  s[t] = cnt[t];
  __syncthreads();
  for (int off = 1; off < 512; off <<= 1) {
    int u = (t >= off) ? s[t - off] : 0;
    __syncthreads();
    s[t] += u;
    __syncthreads();
  }
  int node = b * 512 + t;
  int excl = s[t] - cnt[t];
  if (node < NN) {
    row_ptr[node] = r0 + excl;
    dinv[node] = rsqrtf((float)(cnt[t] + 1));  // +1 self-loop
  }
  cur[t] = r0 + excl;
  __syncthreads();
  for (int e = r0 + t; e < r1; e += 512) {
    int v = edge_buf[e];
    int dl = ((unsigned)v) >> 17;
    int pos = atomicAdd(&cur[dl], 1);
    csr_src[pos] = v & 0x1FFFF;
  }
}

// ---------------- fp32 GEMM v3: out[N,128] = A[N,128] @ W[128,128] ----------------
// 256-row tile, 256 threads, thread-tile 8 rows x 16 cols, K-tile 32.
// Output either fp32 (outf) or packed fp16 (outh, for the gather-bound m buffer).

__global__ __launch_bounds__(256, 2) void gemm256(const float* __restrict__ A,
                                                  const float* __restrict__ W,
                                                  float* __restrict__ outf,
                                                  __half* __restrict__ outh,
                                                  const float* __restrict__ bias,
                                                  int relu,
                                                  const float* __restrict__ rowscale,
                                                  int N) {
  __shared__ float sA[256 * 36];   // row r at sA[r*36], 32 floats used
  __shared__ float sW[32 * 132];   // k-row at sW[k*132], 128 floats used
  const int tid = threadIdx.x;
  const int rg = tid >> 3;   // 0..31
  const int cg = tid & 7;    // 0..7
  const int rowBase = blockIdx.x * 256;

  float4 acc[8][4];
#pragma unroll
  for (int i = 0; i < 8; ++i)
#pragma unroll
    for (int q = 0; q < 4; ++q) acc[i][q] = make_float4(0.f, 0.f, 0.f, 0.f);

  for (int kc = 0; kc < 128; kc += 32) {
    // stage A: per rep, 32 rows x 8 f4-cols; lane = (row%32, f4col) -> coalesced
#pragma unroll
    for (int rep = 0; rep < 8; ++rep) {
      int rl = rep * 32 + (tid >> 3);
      int row = rowBase + rl;
      float4 v = make_float4(0.f, 0.f, 0.f, 0.f);
      if (row < N) v = *(const float4*)&A[(size_t)row * 128 + kc + (tid & 7) * 4];
      *(float4*)&sA[rl * 36 + (tid & 7) * 4] = v;
    }
    // stage W: k = tid>>3 (0..31), 4 f4 at (tid&7)+8j -> coalesced
    {
      int k = tid >> 3;
      const float* src = &W[(size_t)(kc + k) * 128];
#pragma unroll
      for (int j = 0; j < 4; ++j) {
        int f4 = (tid & 7) + 8 * j;
        *(float4*)&sW[k * 132 + f4 * 4] = *(const float4*)&src[f4 * 4];
      }
    }
    __syncthreads();

#pragma unroll
    for (int kk = 0; kk < 32; kk += 4) {
      float4 a[8];
#pragma unroll
      for (int i = 0; i < 8; ++i)
        a[i] = *(float4*)&sA[(rg + 32 * i) * 36 + kk];
#pragma unroll
      for (int j = 0; j < 4; ++j) {
        float4 b[4];
#pragma unroll
        for (int q = 0; q < 4; ++q)
          b[q] = *(float4*)&sW[(kk + j) * 132 + (cg + 8 * q) * 4];
#pragma unroll
        for (int i = 0; i < 8; ++i) {
          float av = (j == 0) ? a[i].x : (j == 1) ? a[i].y : (j == 2) ? a[i].z : a[i].w;
#pragma unroll
          for (int q = 0; q < 4; ++q) {
            acc[i][q].x += av * b[q].x;
            acc[i][q].y += av * b[q].y;
            acc[i][q].z += av * b[q].z;
            acc[i][q].w += av * b[q].w;
          }
        }
      }
    }
    __syncthreads();
  }

  float4 bv[4];
#pragma unroll
  for (int q = 0; q < 4; ++q)
    bv[q] = bias ? *(const float4*)&bias[(cg + 8 * q) * 4]
                 : make_float4(0.f, 0.f, 0.f, 0.f);
#pragma unroll
  for (int i = 0; i < 8; ++i) {
    int row = rowBase + rg + 32 * i;
    if (row < N) {
      float sc = rowscale ? rowscale[row] : 1.0f;
#pragma unroll
      for (int q = 0; q < 4; ++q) {
        float4 v;
        v.x = (acc[i][q].x + bv[q].x) * sc;
        v.y = (acc[i][q].y + bv[q].y) * sc;
        v.z = (acc[i][q].z + bv[q].z) * sc;
        v.w = (acc[i][q].w + bv[q].w) * sc;
        if (relu) {
          v.x = fmaxf(v.x, 0.f); v.y = fmaxf(v.y, 0.f);
          v.z = fmaxf(v.z, 0.f); v.w = fmaxf(v.w, 0.f);
        }
        if (outf) {
          *(float4*)&outf[(size_t)row * 128 + (cg + 8 * q) * 4] = v;
        } else {
          __half2* p = (__half2*)&outh[(size_t)row * 128 + (cg + 8 * q) * 4];
          p[0] = __floats2half2_rn(v.x, v.y);
          p[1] = __floats2half2_rn(v.z, v.w);
        }
      }
    }
  }
}

// ---- fused aggregation: h[i] = relu(dinv_i*(sum_in m'[src] + m'[i]) + bias) ----
// m' is fp16 (pre-scaled by dinv[src] in the GEMM epilogue); accumulate fp32.
// 32 lanes per node; each lane owns 4 features = 2x half2 = 8 B per row.

__global__ __launch_bounds__(256) void gather_fused(const __half* __restrict__ m,
                                                    const int* __restrict__ row_ptr,
                                                    const int* __restrict__ csr_src,
                                                    const float* __restrict__ dinv,
                                                    const float* __restrict__ bias,
                                                    float* __restrict__ h) {
  int t = blockIdx.x * 256 + threadIdx.x;
  int node = t >> 5;
  if (node >= NN) return;
  int lane = t & 31;

  float4 a0, a1, a2, a3;
  {
    const __half2* mp = (const __half2*)&m[(size_t)node * 128 + lane * 4];
    float2 f0 = __half22float2(mp[0]);
    float2 f1 = __half22float2(mp[1]);
    a0 = make_float4(f0.x, f0.y, f1.x, f1.y);  // self (pre-scaled)
  }
  a1 = make_float4(0.f, 0.f, 0.f, 0.f);
  a2 = make_float4(0.f, 0.f, 0.f, 0.f);
  a3 = make_float4(0.f, 0.f, 0.f, 0.f);

  int beg = row_ptr[node];
  int end = row_ptr[node + 1];

  int k = beg;
  for (; k + 3 < end; k += 4) {
    int s0 = csr_src[k], s1 = csr_src[k + 1], s2 = csr_src[k + 2], s3 = csr_src[k + 3];
    const __half2* p0 = (const __half2*)&m[(size_t)s0 * 128 + lane * 4];
    const __half2* p1 = (const __half2*)&m[(size_t)s1 * 128 + lane * 4];
    const __half2* p2 = (const __half2*)&m[(size_t)s2 * 128 + lane * 4];
    const __half2* p3 = (const __half2*)&m[(size_t)s3 * 128 + lane * 4];
    float2 v0a = __half22float2(p0[0]), v0b = __half22float2(p0[1]);
    float2 v1a = __half22float2(p1[0]), v1b = __half22float2(p1[1]);
    float2 v2a = __half22float2(p2[0]), v2b = __half22float2(p2[1]);
    float2 v3a = __half22float2(p3[0]), v3b = __half22float2(p3[1]);
    a0.x += v0a.x; a0.y += v0a.y; a0.z += v0b.x; a0.w += v0b.y;
    a1.x += v1a.x; a1.y += v1a.y; a1.z += v1b.x; a1.w += v1b.y;
    a2.x += v2a.x; a2.y += v2a.y; a2.z += v2b.x; a2.w += v2b.y;
    a3.x += v3a.x; a3.y += v3a.y; a3.z += v3b.x; a3.w += v3b.y;
  }
  for (; k < end; ++k) {
    int s = csr_src[k];
    const __half2* p = (const __half2*)&m[(size_t)s * 128 + lane * 4];
    float2 va = __half22float2(p[0]), vb = __half22float2(p[1]);
    a0.x += va.x; a0.y += va.y; a0.z += vb.x; a0.w += vb.y;
  }
  a0.x += a1.x + a2.x + a3.x;
  a0.y += a1.y + a2.y + a3.y;
  a0.z += a1.z + a2.z + a3.z;
  a0.w += a1.w + a2.w + a3.w;

  float dn = dinv[node];
  float4 b = *(const float4*)&bias[lane * 4];
  float4 o;
  o.x = fmaxf(a0.x * dn + b.x, 0.f);
  o.y = fmaxf(a0.y * dn + b.y, 0.f);
  o.z = fmaxf(a0.z * dn + b.z, 0.f);
  o.w = fmaxf(a0.w * dn + b.w, 0.f);
  *(float4*)&h[(size_t)node * 128 + lane * 4] = o;
}

// ---------------- pooling: g[batch[i]] += h[i], batch sorted ----------------

__global__ __launch_bounds__(128) void pool_kernel(const float* __restrict__ h,
                                                   const int* __restrict__ batch,
                                                   float* __restrict__ g) {
  int d = threadIdx.x;
  int chunk = (NN + gridDim.x - 1) / gridDim.x;
  int r0 = blockIdx.x * chunk;
  int r1 = min(NN, r0 + chunk);
  if (r0 >= r1) return;
  float acc = 0.f;
  int cur = batch[r0];
  for (int r = r0; r < r1; ++r) {
    int b = batch[r];
    if (b != cur) {
      atomicAdd(&g[(size_t)cur * HID + d], acc);
      acc = 0.f;
      cur = b;
    }
    acc += h[(size_t)r * HID + d];
  }
  atomicAdd(&g[(size_t)cur * HID + d], acc);
}

// ---------------- decode: out[128,10] = g @ dec_W + dec_b ----------------

__global__ __launch_bounds__(256) void decode_kernel(const float* __restrict__ g,
                                                     const float* __restrict__ W,
                                                     const float* __restrict__ b,
                                                     float* __restrict__ out) {
  int idx = blockIdx.x * 256 + threadIdx.x;
  if (idx >= N_GRAPHS * OUT_DIM) return;
  int gi = idx / OUT_DIM;
  int o = idx % OUT_DIM;
  float acc = b[o];
#pragma unroll 8
  for (int k = 0; k < HID; ++k) acc += g[(size_t)gi * HID + k] * W[k * OUT_DIM + o];
  out[idx] = acc;
}

// ---------------- launch ----------------

extern "C" void kernel_launch(void* const* d_in, const int* in_sizes, int n_in,
                              void* d_out, int out_size, void* d_ws, size_t ws_size,
                              hipStream_t stream) {
  const float* x      = (const float*)d_in[0];
  const float* enc_W  = (const float*)d_in[1];
  const float* enc_b  = (const float*)d_in[2];
  const float* conv_W = (const float*)d_in[3];
  const float* conv_b = (const float*)d_in[4];
  const float* dec_W  = (const float*)d_in[5];
  const float* dec_b  = (const float*)d_in[6];
  const int*   erow   = (const int*)d_in[7];
  const int*   ecol   = ((const int*)d_in[7]) + NE;
  const int*   batch  = (const int*)d_in[8];
  float* out = (float*)d_out;

  float*  h          = (float*)d_ws;               // 12.8M f
  __half* mh         = (__half*)(h + (size_t)12800000);  // 12.8M halves (25.6 MB)
  float*  dinv       = (float*)(mh + (size_t)12800000);  // 100352 f
  float*  g          = dinv + 100352;              // 16384 f
  int*    row_ptr    = (int*)(g + 16384);          // 100352 i (NN+1 used)
  int*    csr_src    = row_ptr + 100352;           // 1.6M i
  int*    edge_buf   = csr_src + 1600000;          // 1.6M i
  int*    coarse_cnt = edge_buf + 1600000;         // 256 i
  int*    bucket_base= coarse_cnt + 256;           // 256 i
  int*    bcur       = bucket_base + 256;          // 256 i

  const int gemmBlocks = (NN + 255) / 256;
  const int nodeBlocks = (NN * 32 + 255) / 256;

  // ---- CSR build (two-level counting sort) ----
  k_zero<<<64, 256, 0, stream>>>(g, coarse_cnt);
  k_hist<<<NCB, 256, 0, stream>>>(ecol, coarse_cnt);
  k_scanb<<<1, 256, 0, stream>>>(coarse_cnt, bucket_base, bcur, row_ptr);
  k_scatter<<<NCB, 256, 0, stream>>>(erow, ecol, bcur, edge_buf);
  k_build<<<NBUCK, 512, 0, stream>>>(bucket_base, edge_buf, row_ptr, dinv, csr_src);

  // ---- encode: h = relu(x @ enc_W + enc_b), fp32 out ----
  gemm256<<<gemmBlocks, 256, 0, stream>>>(x, enc_W, h, nullptr, enc_b, 1, nullptr, NN);

  // ---- conv layers: m' = (h@W)*dinv as fp16, then fused gather ----
  for (int l = 0; l < N_CONV; ++l) {
    const float* Wl = conv_W + (size_t)l * 128 * 128;
    const float* bl = conv_b + (size_t)l * 128;
    gemm256<<<gemmBlocks, 256, 0, stream>>>(h, Wl, nullptr, mh, nullptr, 0, dinv, NN);
    gather_fused<<<nodeBlocks, 256, 0, stream>>>(mh, row_ptr, csr_src, dinv, bl, h);
  }

  // ---- pooling + decode ----
  pool_kernel<<<2048, 128, 0, stream>>>(h, batch, g);
  decode_kernel<<<(N_GRAPHS * OUT_DIM + 255) / 256, 256, 0, stream>>>(g, dec_W, dec_b, out);
}